// Round 1
// 643.684 us; speedup vs baseline: 1.1921x; 1.1921x over previous
//
#include <hip/hip_runtime.h>

#define N_USERS 50000
#define N_ENTITIES 100000
#define N_RELATIONS 16
#define N_EDGES 3200000
#define NNZ 2500000
#define CH 64

#define RPB 64            // destination rows per bucket/block
#define NB_E 1563         // ceil(N_ENTITIES/64)
#define NB_U 782          // ceil(N_USERS/64)
#define CAP_E 2560        // bucket capacity (mean 2047, +11 sigma)
#define CAP_U 3840        // (mean 3197, +11 sigma)
#define P1_BLOCKS 512
#define CHUNK 2048        // edges per block-iteration (was 1024)

__device__ __forceinline__ unsigned short f2bf(float f) {
    unsigned u = __float_as_uint(f);
    u += 0x7FFF + ((u >> 16) & 1);   // round-to-nearest-even
    return (unsigned short)(u >> 16);
}

// ---------------------------------------------------------------------------
// Merged build kernel: KG bucket-binning (blocks [0,512)), user binning
// (blocks [512,1024)), init/residual-copy/bf16-pack (blocks >= 1024).
// Merging lets the three independent phases overlap instead of serializing
// on the stream.
// ---------------------------------------------------------------------------
__global__ void __launch_bounds__(256)
build_kernel(const float4* __restrict__ user_emb,
             const float4* __restrict__ entity_emb,
             ushort4* __restrict__ cur_bf,
             float4* __restrict__ out_entity,
             float4* __restrict__ out_user,
             const int* __restrict__ head, const int* __restrict__ tail,
             const int* __restrict__ type, const float* __restrict__ maskp,
             const int* __restrict__ irows, const int* __restrict__ icols,
             const float* __restrict__ ivals,
             int* __restrict__ cntE, int2* __restrict__ binE,
             int* __restrict__ cntU, int2* __restrict__ binU) {
    __shared__ int hist[NB_E];
    __shared__ int lbase[NB_E];
    const int blk = blockIdx.x;

    if (blk >= 2 * P1_BLOCKS) {
        // ---- init segment: residuals fp32 + bf16 current entity state ----
        const int ne4 = N_ENTITIES * CH / 4;
        const int nu4 = N_USERS * CH / 4;
        int i = (blk - 2 * P1_BLOCKS) * 256 + threadIdx.x;
        if (i < ne4) {
            float4 v = entity_emb[i];
            out_entity[i] = v;
            ushort4 bq;
            bq.x = f2bf(v.x); bq.y = f2bf(v.y); bq.z = f2bf(v.z); bq.w = f2bf(v.w);
            cur_bf[i] = bq;
        }
        if (i < nu4) out_user[i] = user_emb[i];
        return;
    }

    if (blk < P1_BLOCKS) {
        // ---- KG edges: payload tail(17b) | rel(4b)<<17 | rowlocal(6b)<<21 ----
        for (int i = threadIdx.x; i < NB_E; i += blockDim.x) hist[i] = 0;
        __syncthreads();
        const int chunk = (N_EDGES + P1_BLOCKS - 1) / P1_BLOCKS;
        int base = blk * chunk;
        int lim = min(base + chunk, N_EDGES);
        for (int i = base + (int)threadIdx.x; i < lim; i += blockDim.x)
            atomicAdd(&hist[head[i] >> 6], 1);
        __syncthreads();
        for (int i = threadIdx.x; i < NB_E; i += blockDim.x) {
            int c = hist[i];
            lbase[i] = c ? atomicAdd(&cntE[i], c) : 0;
            hist[i] = 0;
        }
        __syncthreads();
        for (int i = base + (int)threadIdx.x; i < lim; i += blockDim.x) {
            int h = head[i];
            int b = h >> 6;
            int loc = lbase[b] + atomicAdd(&hist[b], 1);
            if (loc < CAP_E)
                binE[(size_t)b * CAP_E + loc] =
                    make_int2(tail[i] | ((type[i] - 1) << 17) | ((h & 63) << 21),
                              __float_as_int(maskp[i]));
        }
    } else {
        // ---- user interactions: payload col(17b) | rowlocal(6b)<<17 ----
        const int ub = blk - P1_BLOCKS;
        for (int i = threadIdx.x; i < NB_U; i += blockDim.x) hist[i] = 0;
        __syncthreads();
        const int chunk = (NNZ + P1_BLOCKS - 1) / P1_BLOCKS;
        int base = ub * chunk;
        int lim = min(base + chunk, NNZ);
        for (int i = base + (int)threadIdx.x; i < lim; i += blockDim.x)
            atomicAdd(&hist[irows[i] >> 6], 1);
        __syncthreads();
        for (int i = threadIdx.x; i < NB_U; i += blockDim.x) {
            int c = hist[i];
            lbase[i] = c ? atomicAdd(&cntU[i], c) : 0;
            hist[i] = 0;
        }
        __syncthreads();
        for (int i = base + (int)threadIdx.x; i < lim; i += blockDim.x) {
            int r = irows[i];
            int b = r >> 6;
            int loc = lbase[b] + atomicAdd(&hist[b], 1);
            if (loc < CAP_U)
                binU[(size_t)b * CAP_U + loc] =
                    make_int2(icols[i] | ((r & 63) << 17), __float_as_int(ivals[i]));
        }
    }
}

// ---------------------------------------------------------------------------
// Aggregation v4: one block (512 thr = 8 waves) per 64-row bucket.
// Per 2048-edge chunk: coalesced payload loads -> LDS counting sort by
// rowlocal -> wave w accumulates rows 8w..8w+7 in registers.
// NEW: split-wave gather — lanes 0-31 process edge i, lanes 32-63 edge i+1;
// each lane loads ONE dword (2 packed bf16) and accumulates BOTH channels
// (2c, 2c+1). Halves VMEM instructions/edge (no 2-lane redundancy), ~halves
// VALU/edge (no hi/lo cndmask select), and doubles gather MLP via 4-edge
// unroll. Halves merged with one shfl_xor(32) in the epilogue.
// ---------------------------------------------------------------------------
__global__ void __launch_bounds__(512)
agg_kernel(const unsigned int* __restrict__ cur32,   // bf16 pairs, 32 dwords/row
           const float* __restrict__ weight,
           const int2* __restrict__ binE, const int* __restrict__ cntE,
           const int2* __restrict__ binU, const int* __restrict__ cntU,
           unsigned short* __restrict__ nxt,
           float* __restrict__ res_e, float* __restrict__ res_u) {
    __shared__ int2  sorted[CHUNK];            // 16 KB
    __shared__ int   hist[RPB];                // 256 B
    __shared__ int   offs[RPB + 1];            // 260 B
    __shared__ float wlds[N_RELATIONS * CH];   // 4 KB

    const int b = blockIdx.x;
    const int t = threadIdx.x;
    const int w = t >> 6;        // wave 0..7
    const int lane = t & 63;
    const int h = lane >> 5;     // which edge of the pair this half-wave owns
    const int c = lane & 31;     // dword (channel-pair) index within the row
    const bool is_user = (b < NB_U);
    const int eb = b - NB_U;
    const int2* __restrict__ bin = is_user ? (binU + (size_t)b * CAP_U)
                                           : (binE + (size_t)eb * CAP_E);
    const int cnt = is_user ? min(cntU[b], CAP_U) : min(cntE[eb], CAP_E);
    const int rsh = is_user ? 17 : 21;    // rowlocal bit position

    if (!is_user)
        for (int i = t; i < N_RELATIONS * CH; i += 512) wlds[i] = weight[i];
    const float2* __restrict__ wl2 = (const float2*)wlds;

    float a0[8], a1[8];
    #pragma unroll
    for (int rr = 0; rr < 8; ++rr) { a0[rr] = 0.f; a1[rr] = 0.f; }

    for (int base = 0; base < cnt; base += CHUNK) {
        const int m = min(CHUNK, cnt - base);
        // issue coalesced payload loads (registers) before touching LDS
        int2 e0, e1, e2, e3;
        int r0 = -1, r1 = -1, r2 = -1, r3 = -1;
        int k0 = 0, k1 = 0, k2 = 0, k3 = 0;
        const int j0 = t, j1 = t + 512, j2 = t + 1024, j3 = t + 1536;
        if (j0 < m) e0 = bin[base + j0];
        if (j1 < m) e1 = bin[base + j1];
        if (j2 < m) e2 = bin[base + j2];
        if (j3 < m) e3 = bin[base + j3];
        if (t < RPB) hist[t] = 0;
        __syncthreads();   // hist cleared; prev chunk fully processed
        if (j0 < m) { r0 = (e0.x >> rsh) & 63; k0 = atomicAdd(&hist[r0], 1); }
        if (j1 < m) { r1 = (e1.x >> rsh) & 63; k1 = atomicAdd(&hist[r1], 1); }
        if (j2 < m) { r2 = (e2.x >> rsh) & 63; k2 = atomicAdd(&hist[r2], 1); }
        if (j3 < m) { r3 = (e3.x >> rsh) & 63; k3 = atomicAdd(&hist[r3], 1); }
        __syncthreads();   // counts final
        if (t < 64) {      // wave 0: exclusive scan of 64 counts
            int v = hist[t];
            int s = v;
            #pragma unroll
            for (int d = 1; d < 64; d <<= 1) {
                int nb = __shfl_up(s, d, 64);
                if (t >= d) s += nb;
            }
            offs[t] = s - v;
            if (t == 63) offs[64] = s;
        }
        __syncthreads();   // offs ready
        if (j0 < m) sorted[offs[r0] + k0] = e0;
        if (j1 < m) sorted[offs[r1] + k1] = e1;
        if (j2 < m) sorted[offs[r2] + k2] = e2;
        if (j3 < m) sorted[offs[r3] + k3] = e3;
        __syncthreads();   // sorted ready

        if (is_user) {
            #pragma unroll
            for (int rr = 0; rr < 8; ++rr) {
                const int row = (w << 3) + rr;
                int s = offs[row], e = offs[row + 1];
                float x0 = a0[rr], x1 = a1[rr];
                int i = s;
                for (; i + 3 < e; i += 4) {
                    int2 p0 = sorted[i + h];
                    int2 p1 = sorted[i + 2 + h];
                    unsigned q0 = cur32[(size_t)(p0.x & 0x1FFFF) * 32 + c];
                    unsigned q1 = cur32[(size_t)(p1.x & 0x1FFFF) * 32 + c];
                    float s0 = __int_as_float(p0.y);
                    float s1 = __int_as_float(p1.y);
                    x0 += __uint_as_float(q0 << 16) * s0;
                    x1 += __uint_as_float(q0 & 0xFFFF0000u) * s0;
                    x0 += __uint_as_float(q1 << 16) * s1;
                    x1 += __uint_as_float(q1 & 0xFFFF0000u) * s1;
                }
                for (; i < e; i += 2) {          // 1..3 leftover edges
                    int idx = i + h;
                    bool vld = idx < e;
                    int2 p = sorted[vld ? idx : i];
                    unsigned q = cur32[(size_t)(p.x & 0x1FFFF) * 32 + c];
                    float s0 = vld ? __int_as_float(p.y) : 0.f;
                    x0 += __uint_as_float(q << 16) * s0;
                    x1 += __uint_as_float(q & 0xFFFF0000u) * s0;
                }
                a0[rr] = x0; a1[rr] = x1;
            }
        } else {
            #pragma unroll
            for (int rr = 0; rr < 8; ++rr) {
                const int row = (w << 3) + rr;
                int s = offs[row], e = offs[row + 1];
                float x0 = a0[rr], x1 = a1[rr];
                int i = s;
                for (; i + 3 < e; i += 4) {
                    int2 p0 = sorted[i + h];
                    int2 p1 = sorted[i + 2 + h];
                    unsigned q0 = cur32[(size_t)(p0.x & 0x1FFFF) * 32 + c];
                    unsigned q1 = cur32[(size_t)(p1.x & 0x1FFFF) * 32 + c];
                    float2 wv0 = wl2[((p0.x >> 17) & 15) * 32 + c];
                    float2 wv1 = wl2[((p1.x >> 17) & 15) * 32 + c];
                    float s0 = __int_as_float(p0.y);
                    float s1 = __int_as_float(p1.y);
                    x0 += __uint_as_float(q0 << 16) * (s0 * wv0.x);
                    x1 += __uint_as_float(q0 & 0xFFFF0000u) * (s0 * wv0.y);
                    x0 += __uint_as_float(q1 << 16) * (s1 * wv1.x);
                    x1 += __uint_as_float(q1 & 0xFFFF0000u) * (s1 * wv1.y);
                }
                for (; i < e; i += 2) {
                    int idx = i + h;
                    bool vld = idx < e;
                    int2 p = sorted[vld ? idx : i];
                    unsigned q = cur32[(size_t)(p.x & 0x1FFFF) * 32 + c];
                    float2 wv = wl2[((p.x >> 17) & 15) * 32 + c];
                    float s0 = vld ? __int_as_float(p.y) : 0.f;
                    x0 += __uint_as_float(q << 16) * (s0 * wv.x);
                    x1 += __uint_as_float(q & 0xFFFF0000u) * (s0 * wv.y);
                }
                a0[rr] = x0; a1[rr] = x1;
            }
        }
        __syncthreads();   // done reading sorted/offs before next chunk rewrites
    }

    // epilogue: merge half-waves, fused L2-normalize + residual (+ next state)
    #pragma unroll
    for (int rr = 0; rr < 8; ++rr) {
        const int row = (w << 3) + rr;
        float x0 = a0[rr] + __shfl_xor(a0[rr], 32, 64);
        float x1 = a1[rr] + __shfl_xor(a1[rr], 32, 64);
        float ss = x0 * x0 + x1 * x1;
        #pragma unroll
        for (int o = 16; o; o >>= 1) ss += __shfl_xor(ss, o, 64);
        float inv = 1.f / fmaxf(sqrtf(ss), 1e-12f);
        float y0 = x0 * inv, y1 = x1 * inv;
        if (h == 0) {      // lanes 0-31 hold the complete row; write float2
            if (is_user) {
                int grow = b * RPB + row;
                if (grow < N_USERS) {
                    float2* p = (float2*)res_u + (size_t)grow * 32 + c;
                    float2 v = *p; v.x += y0; v.y += y1; *p = v;
                }
            } else {
                int grow = eb * RPB + row;
                if (grow < N_ENTITIES) {
                    ((unsigned*)nxt)[(size_t)grow * 32 + c] =
                        (unsigned)f2bf(y0) | ((unsigned)f2bf(y1) << 16);
                    float2* p = (float2*)res_e + (size_t)grow * 32 + c;
                    float2 v = *p; v.x += y0; v.y += y1; *p = v;
                }
            }
        }
    }
}

extern "C" void kernel_launch(void* const* d_in, const int* in_sizes, int n_in,
                              void* d_out, int out_size, void* d_ws, size_t ws_size,
                              hipStream_t stream) {
    const float* user_emb   = (const float*)d_in[0];
    const float* entity_emb = (const float*)d_in[1];
    const float* weight     = (const float*)d_in[2];
    const float* mask       = (const float*)d_in[3];
    const float* ivals      = (const float*)d_in[4];
    const int*   edge_head  = (const int*)d_in[5];
    const int*   edge_tail  = (const int*)d_in[6];
    const int*   edge_type  = (const int*)d_in[7];
    const int*   irows      = (const int*)d_in[8];
    const int*   icols      = (const int*)d_in[9];

    float* out_entity = (float*)d_out;
    float* out_user   = (float*)d_out + (size_t)N_ENTITIES * CH;

    // ---- workspace layout ----
    unsigned short* curA = (unsigned short*)d_ws;                 // 12.8 MB
    unsigned short* curB = curA + (size_t)N_ENTITIES * CH;        // 12.8 MB
    int2* binE = (int2*)(curB + (size_t)N_ENTITIES * CH);         // 32 MB
    int2* binU = binE + (size_t)NB_E * CAP_E;                     // 24 MB
    int*  cntE = (int*)(binU + (size_t)NB_U * CAP_U);             // 1563
    int*  cntU = cntE + NB_E;                                     // 782

    // ---- build: binning (both graphs) + init, one overlapped launch ----
    hipMemsetAsync(cntE, 0, (size_t)(NB_E + NB_U) * sizeof(int), stream);
    {
        const int init_blocks = (N_ENTITIES * CH / 4 + 255) / 256;   // 6250
        build_kernel<<<2 * P1_BLOCKS + init_blocks, 256, 0, stream>>>(
            (const float4*)user_emb, (const float4*)entity_emb,
            (ushort4*)curA, (float4*)out_entity, (float4*)out_user,
            edge_head, edge_tail, edge_type, mask,
            irows, icols, ivals,
            cntE, binE, cntU, binU);
    }

    // ---- 2 hops, double-buffered bf16 entity state ----
    agg_kernel<<<NB_U + NB_E, 512, 0, stream>>>(
        (const unsigned int*)curA, weight, binE, cntE, binU, cntU,
        curB, out_entity, out_user);
    agg_kernel<<<NB_U + NB_E, 512, 0, stream>>>(
        (const unsigned int*)curB, weight, binE, cntE, binU, cntU,
        curA, out_entity, out_user);
}

// Round 2
// 630.328 us; speedup vs baseline: 1.2174x; 1.0212x over previous
//
#include <hip/hip_runtime.h>

#define N_USERS 50000
#define N_ENTITIES 100000
#define N_RELATIONS 16
#define N_EDGES 3200000
#define NNZ 2500000
#define CH 64

#define RPB 64            // destination rows per bucket/block
#define NB_E 1563         // ceil(N_ENTITIES/64)
#define NB_U 782          // ceil(N_USERS/64)
#define CAP_E 2560        // bucket capacity (mean 2047, +11 sigma)
#define CAP_U 3840        // (mean 3197, +11 sigma)
#define P1_BLOCKS 512

__device__ __forceinline__ unsigned short f2bf(float f) {
    unsigned u = __float_as_uint(f);
    u += 0x7FFF + ((u >> 16) & 1);   // round-to-nearest-even
    return (unsigned short)(u >> 16);
}

// ---------------------------------------------------------------------------
// Merged build kernel: KG bucket-binning (blocks [0,512)), user binning
// (blocks [512,1024)), init/residual-copy/bf16-pack (blocks >= 1024).
// ---------------------------------------------------------------------------
__global__ void __launch_bounds__(256)
build_kernel(const float4* __restrict__ user_emb,
             const float4* __restrict__ entity_emb,
             ushort4* __restrict__ cur_bf,
             float4* __restrict__ out_entity,
             float4* __restrict__ out_user,
             const int* __restrict__ head, const int* __restrict__ tail,
             const int* __restrict__ type, const float* __restrict__ maskp,
             const int* __restrict__ irows, const int* __restrict__ icols,
             const float* __restrict__ ivals,
             int* __restrict__ cntE, int2* __restrict__ binE,
             int* __restrict__ cntU, int2* __restrict__ binU) {
    __shared__ int hist[NB_E];
    __shared__ int lbase[NB_E];
    const int blk = blockIdx.x;

    if (blk >= 2 * P1_BLOCKS) {
        const int ne4 = N_ENTITIES * CH / 4;
        const int nu4 = N_USERS * CH / 4;
        int i = (blk - 2 * P1_BLOCKS) * 256 + threadIdx.x;
        if (i < ne4) {
            float4 v = entity_emb[i];
            out_entity[i] = v;
            ushort4 bq;
            bq.x = f2bf(v.x); bq.y = f2bf(v.y); bq.z = f2bf(v.z); bq.w = f2bf(v.w);
            cur_bf[i] = bq;
        }
        if (i < nu4) out_user[i] = user_emb[i];
        return;
    }

    if (blk < P1_BLOCKS) {
        // KG edges: payload tail(17b) | rel(4b)<<17 | rowlocal(6b)<<21
        for (int i = threadIdx.x; i < NB_E; i += blockDim.x) hist[i] = 0;
        __syncthreads();
        const int chunk = (N_EDGES + P1_BLOCKS - 1) / P1_BLOCKS;
        int base = blk * chunk;
        int lim = min(base + chunk, N_EDGES);
        for (int i = base + (int)threadIdx.x; i < lim; i += blockDim.x)
            atomicAdd(&hist[head[i] >> 6], 1);
        __syncthreads();
        for (int i = threadIdx.x; i < NB_E; i += blockDim.x) {
            int c = hist[i];
            lbase[i] = c ? atomicAdd(&cntE[i], c) : 0;
            hist[i] = 0;
        }
        __syncthreads();
        for (int i = base + (int)threadIdx.x; i < lim; i += blockDim.x) {
            int h = head[i];
            int b = h >> 6;
            int loc = lbase[b] + atomicAdd(&hist[b], 1);
            if (loc < CAP_E)
                binE[(size_t)b * CAP_E + loc] =
                    make_int2(tail[i] | ((type[i] - 1) << 17) | ((h & 63) << 21),
                              __float_as_int(maskp[i]));
        }
    } else {
        // user interactions: payload col(17b) | rowlocal(6b)<<17
        const int ub = blk - P1_BLOCKS;
        for (int i = threadIdx.x; i < NB_U; i += blockDim.x) hist[i] = 0;
        __syncthreads();
        const int chunk = (NNZ + P1_BLOCKS - 1) / P1_BLOCKS;
        int base = ub * chunk;
        int lim = min(base + chunk, NNZ);
        for (int i = base + (int)threadIdx.x; i < lim; i += blockDim.x)
            atomicAdd(&hist[irows[i] >> 6], 1);
        __syncthreads();
        for (int i = threadIdx.x; i < NB_U; i += blockDim.x) {
            int c = hist[i];
            lbase[i] = c ? atomicAdd(&cntU[i], c) : 0;
            hist[i] = 0;
        }
        __syncthreads();
        for (int i = base + (int)threadIdx.x; i < lim; i += blockDim.x) {
            int r = irows[i];
            int b = r >> 6;
            int loc = lbase[b] + atomicAdd(&hist[b], 1);
            if (loc < CAP_U)
                binU[(size_t)b * CAP_U + loc] =
                    make_int2(icols[i] | ((r & 63) << 17), __float_as_int(ivals[i]));
        }
    }
}

// ---------------------------------------------------------------------------
// One-shot bucket sort: counting-sort each bucket by rowlocal IN PLACE
// (whole bucket staged in LDS, <=3840 entries * 8B * 2 buffers = 60KB),
// emit per-bucket rowptr[65]. Paid once; both agg hops then consume
// row-contiguous segments with zero sort/barrier work.
// ---------------------------------------------------------------------------
__global__ void __launch_bounds__(512)
sort_kernel(int2* __restrict__ binE, const int* __restrict__ cntE,
            int2* __restrict__ binU, const int* __restrict__ cntU,
            int* __restrict__ rowptr) {
    __shared__ int2 buf[CAP_U];       // 30720 B
    __shared__ int2 sbuf[CAP_U];      // 30720 B
    __shared__ int  hist[RPB];
    __shared__ int  offs[RPB + 1];

    const int b = blockIdx.x;
    const int t = threadIdx.x;
    const bool is_user = (b < NB_U);
    const int eb = b - NB_U;
    int2* __restrict__ bin = is_user ? (binU + (size_t)b * CAP_U)
                                     : (binE + (size_t)eb * CAP_E);
    const int cnt = is_user ? min(cntU[b], CAP_U) : min(cntE[eb], CAP_E);
    const int rsh = is_user ? 17 : 21;

    if (t < RPB) hist[t] = 0;
    for (int i = t; i < cnt; i += 512) buf[i] = bin[i];
    __syncthreads();
    for (int i = t; i < cnt; i += 512)
        atomicAdd(&hist[(buf[i].x >> rsh) & 63], 1);
    __syncthreads();
    if (t < 64) {        // wave 0: exclusive scan of 64 counts
        int v = hist[t];
        int s = v;
        #pragma unroll
        for (int d = 1; d < 64; d <<= 1) {
            int nb = __shfl_up(s, d, 64);
            if (t >= d) s += nb;
        }
        offs[t] = s - v;
        if (t == 63) offs[64] = s;
    }
    __syncthreads();
    if (t < RPB) hist[t] = 0;        // becomes cursor
    __syncthreads();
    for (int i = t; i < cnt; i += 512) {
        int2 p = buf[i];
        int r = (p.x >> rsh) & 63;
        int k = atomicAdd(&hist[r], 1);
        sbuf[offs[r] + k] = p;
    }
    __syncthreads();
    for (int i = t; i < cnt; i += 512) bin[i] = sbuf[i];   // coalesced writeback
    if (t <= 64) rowptr[b * 65 + t] = offs[t];
}

// ---------------------------------------------------------------------------
// Aggregation v5: pure-gather. One block (512 thr = 8 waves) per bucket;
// wave w owns rows 8w..8w+7, each row is a contiguous payload segment
// [rp[row], rp[row+1]) in the pre-sorted bin. No LDS staging, no barriers
// in the main loop. Split-wave gather: lanes 0-31 = edge i, lanes 32-63 =
// edge i+1; each lane loads one dword (2 packed bf16). 8-edge unroll keeps
// 4 independent payload->gather chains in flight. Per-row fused epilogue
// (merge halves, L2-normalize, residual, next-state).
// ---------------------------------------------------------------------------
__global__ void __launch_bounds__(512)
agg_kernel(const unsigned int* __restrict__ cur32,   // bf16 pairs, 32 dwords/row
           const float* __restrict__ weight,
           const int2* __restrict__ binE, const int2* __restrict__ binU,
           const int* __restrict__ rowptr,
           unsigned short* __restrict__ nxt,
           float* __restrict__ res_e, float* __restrict__ res_u) {
    __shared__ float wlds[N_RELATIONS * CH];   // 4 KB

    const int b = blockIdx.x;
    const int t = threadIdx.x;
    const int w = t >> 6;        // wave 0..7
    const int lane = t & 63;
    const int h = lane >> 5;     // which edge of the pair this half-wave owns
    const int c = lane & 31;     // dword (channel-pair) index within the row
    const bool is_user = (b < NB_U);
    const int eb = b - NB_U;
    const int2* __restrict__ bin = is_user ? (binU + (size_t)b * CAP_U)
                                           : (binE + (size_t)eb * CAP_E);
    const int* __restrict__ rp = rowptr + b * 65;

    if (!is_user)
        for (int i = t; i < N_RELATIONS * CH; i += 512) wlds[i] = weight[i];
    __syncthreads();
    const float2* __restrict__ wl2 = (const float2*)wlds;

    #pragma unroll
    for (int rr = 0; rr < 8; ++rr) {
        const int row = (w << 3) + rr;
        const int s = rp[row], e = rp[row + 1];
        float x0 = 0.f, x1 = 0.f;
        int i = s;
        if (is_user) {
            for (; i + 7 < e; i += 8) {
                int2 p0 = bin[i + h];
                int2 p1 = bin[i + 2 + h];
                int2 p2 = bin[i + 4 + h];
                int2 p3 = bin[i + 6 + h];
                unsigned q0 = cur32[(size_t)(p0.x & 0x1FFFF) * 32 + c];
                unsigned q1 = cur32[(size_t)(p1.x & 0x1FFFF) * 32 + c];
                unsigned q2 = cur32[(size_t)(p2.x & 0x1FFFF) * 32 + c];
                unsigned q3 = cur32[(size_t)(p3.x & 0x1FFFF) * 32 + c];
                float s0 = __int_as_float(p0.y);
                float s1 = __int_as_float(p1.y);
                float s2 = __int_as_float(p2.y);
                float s3 = __int_as_float(p3.y);
                x0 += __uint_as_float(q0 << 16) * s0;
                x1 += __uint_as_float(q0 & 0xFFFF0000u) * s0;
                x0 += __uint_as_float(q1 << 16) * s1;
                x1 += __uint_as_float(q1 & 0xFFFF0000u) * s1;
                x0 += __uint_as_float(q2 << 16) * s2;
                x1 += __uint_as_float(q2 & 0xFFFF0000u) * s2;
                x0 += __uint_as_float(q3 << 16) * s3;
                x1 += __uint_as_float(q3 & 0xFFFF0000u) * s3;
            }
            for (; i < e; i += 2) {          // 1..7 leftover edges, pair-wise
                int idx = i + h;
                bool vld = idx < e;
                int2 p = bin[vld ? idx : i];
                unsigned q = cur32[(size_t)(p.x & 0x1FFFF) * 32 + c];
                float s0 = vld ? __int_as_float(p.y) : 0.f;
                x0 += __uint_as_float(q << 16) * s0;
                x1 += __uint_as_float(q & 0xFFFF0000u) * s0;
            }
        } else {
            for (; i + 7 < e; i += 8) {
                int2 p0 = bin[i + h];
                int2 p1 = bin[i + 2 + h];
                int2 p2 = bin[i + 4 + h];
                int2 p3 = bin[i + 6 + h];
                unsigned q0 = cur32[(size_t)(p0.x & 0x1FFFF) * 32 + c];
                unsigned q1 = cur32[(size_t)(p1.x & 0x1FFFF) * 32 + c];
                unsigned q2 = cur32[(size_t)(p2.x & 0x1FFFF) * 32 + c];
                unsigned q3 = cur32[(size_t)(p3.x & 0x1FFFF) * 32 + c];
                float2 w0 = wl2[((p0.x >> 17) & 15) * 32 + c];
                float2 w1 = wl2[((p1.x >> 17) & 15) * 32 + c];
                float2 w2 = wl2[((p2.x >> 17) & 15) * 32 + c];
                float2 w3 = wl2[((p3.x >> 17) & 15) * 32 + c];
                float s0 = __int_as_float(p0.y);
                float s1 = __int_as_float(p1.y);
                float s2 = __int_as_float(p2.y);
                float s3 = __int_as_float(p3.y);
                x0 += __uint_as_float(q0 << 16) * (s0 * w0.x);
                x1 += __uint_as_float(q0 & 0xFFFF0000u) * (s0 * w0.y);
                x0 += __uint_as_float(q1 << 16) * (s1 * w1.x);
                x1 += __uint_as_float(q1 & 0xFFFF0000u) * (s1 * w1.y);
                x0 += __uint_as_float(q2 << 16) * (s2 * w2.x);
                x1 += __uint_as_float(q2 & 0xFFFF0000u) * (s2 * w2.y);
                x0 += __uint_as_float(q3 << 16) * (s3 * w3.x);
                x1 += __uint_as_float(q3 & 0xFFFF0000u) * (s3 * w3.y);
            }
            for (; i < e; i += 2) {
                int idx = i + h;
                bool vld = idx < e;
                int2 p = bin[vld ? idx : i];
                unsigned q = cur32[(size_t)(p.x & 0x1FFFF) * 32 + c];
                float2 wv = wl2[((p.x >> 17) & 15) * 32 + c];
                float s0 = vld ? __int_as_float(p.y) : 0.f;
                x0 += __uint_as_float(q << 16) * (s0 * wv.x);
                x1 += __uint_as_float(q & 0xFFFF0000u) * (s0 * wv.y);
            }
        }

        // per-row fused epilogue: merge half-waves, L2-normalize, write out
        x0 += __shfl_xor(x0, 32, 64);
        x1 += __shfl_xor(x1, 32, 64);
        float ss = x0 * x0 + x1 * x1;
        #pragma unroll
        for (int o = 16; o; o >>= 1) ss += __shfl_xor(ss, o, 64);
        float inv = 1.f / fmaxf(sqrtf(ss), 1e-12f);
        float y0 = x0 * inv, y1 = x1 * inv;
        if (h == 0) {      // lanes 0-31 hold the complete row; write float2
            if (is_user) {
                int grow = b * RPB + row;
                if (grow < N_USERS) {
                    float2* p = (float2*)res_u + (size_t)grow * 32 + c;
                    float2 v = *p; v.x += y0; v.y += y1; *p = v;
                }
            } else {
                int grow = eb * RPB + row;
                if (grow < N_ENTITIES) {
                    ((unsigned*)nxt)[(size_t)grow * 32 + c] =
                        (unsigned)f2bf(y0) | ((unsigned)f2bf(y1) << 16);
                    float2* p = (float2*)res_e + (size_t)grow * 32 + c;
                    float2 v = *p; v.x += y0; v.y += y1; *p = v;
                }
            }
        }
    }
}

extern "C" void kernel_launch(void* const* d_in, const int* in_sizes, int n_in,
                              void* d_out, int out_size, void* d_ws, size_t ws_size,
                              hipStream_t stream) {
    const float* user_emb   = (const float*)d_in[0];
    const float* entity_emb = (const float*)d_in[1];
    const float* weight     = (const float*)d_in[2];
    const float* mask       = (const float*)d_in[3];
    const float* ivals      = (const float*)d_in[4];
    const int*   edge_head  = (const int*)d_in[5];
    const int*   edge_tail  = (const int*)d_in[6];
    const int*   edge_type  = (const int*)d_in[7];
    const int*   irows      = (const int*)d_in[8];
    const int*   icols      = (const int*)d_in[9];

    float* out_entity = (float*)d_out;
    float* out_user   = (float*)d_out + (size_t)N_ENTITIES * CH;

    // ---- workspace layout ----
    unsigned short* curA = (unsigned short*)d_ws;                 // 12.8 MB
    unsigned short* curB = curA + (size_t)N_ENTITIES * CH;        // 12.8 MB
    int2* binE = (int2*)(curB + (size_t)N_ENTITIES * CH);         // 32 MB
    int2* binU = binE + (size_t)NB_E * CAP_E;                     // 24 MB
    int*  cntE = (int*)(binU + (size_t)NB_U * CAP_U);             // 1563
    int*  cntU = cntE + NB_E;                                     // 782
    int*  rowptr = cntU + NB_U;                                   // 2345*65 = 0.61 MB

    // ---- build: binning (both graphs) + init, one overlapped launch ----
    hipMemsetAsync(cntE, 0, (size_t)(NB_E + NB_U) * sizeof(int), stream);
    {
        const int init_blocks = (N_ENTITIES * CH / 4 + 255) / 256;   // 6250
        build_kernel<<<2 * P1_BLOCKS + init_blocks, 256, 0, stream>>>(
            (const float4*)user_emb, (const float4*)entity_emb,
            (ushort4*)curA, (float4*)out_entity, (float4*)out_user,
            edge_head, edge_tail, edge_type, mask,
            irows, icols, ivals,
            cntE, binE, cntU, binU);
    }

    // ---- one-shot in-place bucket sort + rowptr ----
    sort_kernel<<<NB_U + NB_E, 512, 0, stream>>>(binE, cntE, binU, cntU, rowptr);

    // ---- 2 hops, double-buffered bf16 entity state ----
    agg_kernel<<<NB_U + NB_E, 512, 0, stream>>>(
        (const unsigned int*)curA, weight, binE, binU, rowptr,
        curB, out_entity, out_user);
    agg_kernel<<<NB_U + NB_E, 512, 0, stream>>>(
        (const unsigned int*)curB, weight, binE, binU, rowptr,
        curA, out_entity, out_user);
}